// Round 1
// baseline (379.292 us; speedup 1.0000x reference)
//
#include <hip/hip_runtime.h>

typedef __bf16 bf16x8 __attribute__((ext_vector_type(8)));
typedef float f32x4 __attribute__((ext_vector_type(4)));
typedef unsigned short u16x8 __attribute__((ext_vector_type(8)));
typedef unsigned short u16x4 __attribute__((ext_vector_type(4)));

__device__ __forceinline__ unsigned short f2bf_bits(float f) {
  unsigned u = __float_as_uint(f);
  return (unsigned short)((u + 0x7FFFu + ((u >> 16) & 1u)) >> 16);
}

__device__ __forceinline__ void gload16(const void* g, void* l) {
  __builtin_amdgcn_global_load_lds(
      (const __attribute__((address_space(1))) unsigned int*)g,
      (__attribute__((address_space(3))) unsigned int*)l, 16, 0, 0);
}

// ---------------- weight convert + transpose: src[R][C] f32 -> dst[C][R] bf16
__global__ __launch_bounds__(256) void wconv_t(const float* __restrict__ src,
                                               unsigned short* __restrict__ dst,
                                               int R, int C) {
  __shared__ float tile[32][33];
  const int tx = threadIdx.x & 31, ty = threadIdx.x >> 5;
  const size_t c0 = (size_t)blockIdx.x * 32, r0 = (size_t)blockIdx.y * 32;
#pragma unroll
  for (int i = 0; i < 4; i++)
    tile[ty + i * 8][tx] = src[(r0 + ty + i * 8) * C + c0 + tx];
  __syncthreads();
#pragma unroll
  for (int i = 0; i < 4; i++) {
    int c = ty + i * 8;
    dst[(c0 + c) * R + r0 + tx] = f2bf_bits(tile[tx][c]);
  }
}

// ---------------- LayerNorm: x[row][1024] f32 -> out bf16
__global__ __launch_bounds__(256) void ln_k(const float* __restrict__ x,
                                            const float* __restrict__ g,
                                            const float* __restrict__ be,
                                            unsigned short* __restrict__ o) {
  const int row = blockIdx.x, tid = threadIdx.x;
  const float4 v = ((const float4*)(x + (size_t)row * 1024))[tid];
  float s = v.x + v.y + v.z + v.w;
  float s2 = v.x * v.x + v.y * v.y + v.z * v.z + v.w * v.w;
#pragma unroll
  for (int m = 1; m < 64; m <<= 1) {
    s += __shfl_xor(s, m);
    s2 += __shfl_xor(s2, m);
  }
  __shared__ float red[8];
  const int w = tid >> 6;
  if ((tid & 63) == 0) { red[w] = s; red[4 + w] = s2; }
  __syncthreads();
  s = red[0] + red[1] + red[2] + red[3];
  s2 = red[4] + red[5] + red[6] + red[7];
  const float mu = s * (1.f / 1024.f);
  const float rs_ = rsqrtf(s2 * (1.f / 1024.f) - mu * mu + 1e-5f);
  const float4 gg = ((const float4*)g)[tid];
  const float4 bb = ((const float4*)be)[tid];
  u16x4 pack;
  pack.x = f2bf_bits((v.x - mu) * rs_ * gg.x + bb.x);
  pack.y = f2bf_bits((v.y - mu) * rs_ * gg.y + bb.y);
  pack.z = f2bf_bits((v.z - mu) * rs_ * gg.z + bb.z);
  pack.w = f2bf_bits((v.w - mu) * rs_ * gg.w + bb.w);
  *(u16x4*)(o + (size_t)row * 1024 + tid * 4) = pack;
}

// ---------------- GEMM: C[M][N] = epi(A[M][K] @ Bt[N][K]^T + bias [+ res])
// EPI 0: bf16 store. 1: +bias +res(f32), f32 store. 2: +bias, relu, bf16 store.
template <int EPI>
__global__ __launch_bounds__(256) void gemm_bt(
    const unsigned short* __restrict__ A, const unsigned short* __restrict__ Bt,
    const float* __restrict__ bias, const float* __restrict__ res,
    void* __restrict__ Cv, int M, int N, int K) {
  __shared__ __align__(16) unsigned short As[128 * 64];
  __shared__ __align__(16) unsigned short Bs[128 * 64];
  const int tid = threadIdx.x, lane = tid & 63, w = tid >> 6;
  const int lo = lane & 15, hi = lane >> 4;
  const int l8 = lane >> 3, l7 = lane & 7;
  const int scol = ((l7 ^ l8) << 3);  // swizzled source col (elements)
  const size_t rowBase = (size_t)blockIdx.y * 128;
  const size_t colBase = (size_t)blockIdx.x * 128;
  f32x4 acc[4][4];
#pragma unroll
  for (int i = 0; i < 4; i++)
#pragma unroll
    for (int j = 0; j < 4; j++) acc[i][j] = (f32x4){0.f, 0.f, 0.f, 0.f};
  const int wr = (w >> 1) * 64, wc = (w & 1) * 64;
  const unsigned short* aSrc = A + (rowBase + (size_t)w * 32 + l8) * K + scol;
  const unsigned short* bSrc = Bt + (colBase + (size_t)w * 32 + l8) * K + scol;
  for (int kb = 0; kb < K; kb += 64) {
    __syncthreads();
#pragma unroll
    for (int c = 0; c < 4; c++) {
      gload16(aSrc + (size_t)c * 8 * K + kb, &As[(w * 4 + c) * 512]);
      gload16(bSrc + (size_t)c * 8 * K + kb, &Bs[(w * 4 + c) * 512]);
    }
    __syncthreads();
#pragma unroll
    for (int ks = 0; ks < 2; ks++) {
      bf16x8 af[4], bfr[4];
      const int kbyte = ks * 64 + (hi << 4);
#pragma unroll
      for (int i = 0; i < 4; i++) {
        const int ar = wr + i * 16 + lo;
        af[i] = *(const bf16x8*)((const char*)As + ar * 128 + (kbyte ^ ((ar & 7) << 4)));
        const int br = wc + i * 16 + lo;
        bfr[i] = *(const bf16x8*)((const char*)Bs + br * 128 + (kbyte ^ ((br & 7) << 4)));
      }
#pragma unroll
      for (int i = 0; i < 4; i++)
#pragma unroll
        for (int j = 0; j < 4; j++)
          acc[i][j] = __builtin_amdgcn_mfma_f32_16x16x32_bf16(af[i], bfr[j], acc[i][j], 0, 0, 0);
    }
  }
#pragma unroll
  for (int i = 0; i < 4; i++) {
#pragma unroll
    for (int r = 0; r < 4; r++) {
      const size_t row = rowBase + wr + i * 16 + hi * 4 + r;
#pragma unroll
      for (int j = 0; j < 4; j++) {
        const size_t col = colBase + wc + j * 16 + lo;
        float v = acc[i][j][r];
        if (EPI >= 1) v += bias[col];
        if (EPI == 1) {
          ((float*)Cv)[row * N + col] = v + res[row * N + col];
        } else if (EPI == 2) {
          ((unsigned short*)Cv)[row * N + col] = f2bf_bits(fmaxf(v, 0.f));
        } else {
          ((unsigned short*)Cv)[row * N + col] = f2bf_bits(v);
        }
      }
    }
  }
}

// ---------------- flash attention: grid (S/64, H, N); 4 waves, 16 q-rows each
__global__ __launch_bounds__(256) void attn_k(const unsigned short* __restrict__ Q,
                                              const unsigned short* __restrict__ K,
                                              const unsigned short* __restrict__ V,
                                              unsigned short* __restrict__ O) {
  __shared__ __align__(16) unsigned short Ks[64 * 64];
  __shared__ __align__(16) unsigned short Vt[64 * 64];  // Vt[d][kv] (swizzled)
  __shared__ __align__(16) unsigned short Ps[4][16 * 64];
  const int tid = threadIdx.x, lane = tid & 63, w = tid >> 6;
  const int lo = lane & 15, hi = lane >> 4;
  const int l8 = lane >> 3, l7 = lane & 7;
  const int scol = ((l7 ^ l8) << 3);
  const int h = blockIdx.y, n = blockIdx.z;
  const size_t tRow0 = (size_t)n * 2048;
  const int colBase = h * 64;
  // Q fragments (row = lo, k contiguous)
  const unsigned short* qrow = Q + (tRow0 + blockIdx.x * 64 + w * 16 + lo) * 1024 + colBase;
  const bf16x8 qf0 = *(const bf16x8*)(qrow + hi * 8);
  const bf16x8 qf1 = *(const bf16x8*)(qrow + 32 + hi * 8);
  float m_r[4], l_r[4];
  f32x4 oacc[4];
#pragma unroll
  for (int r = 0; r < 4; r++) { m_r[r] = -1e30f; l_r[r] = 0.f; }
#pragma unroll
  for (int d = 0; d < 4; d++) oacc[d] = (f32x4){0.f, 0.f, 0.f, 0.f};

  for (int kv0 = 0; kv0 < 2048; kv0 += 64) {
    __syncthreads();  // previous iter LDS reads done
    // stage K tile (swizzled source, linear LDS dest)
#pragma unroll
    for (int c = 0; c < 4; c++) {
      const int chunk = w * 4 + c;
      const size_t r = chunk * 8 + l8;
      gload16(K + (tRow0 + kv0 + r) * 1024 + colBase + scol, &Ks[chunk * 512]);
    }
    // stage V transposed (reg staging, swizzled LDS writes)
    {
      const int kv = tid & 63, dg = tid >> 6;
      const unsigned short* vrow = V + (tRow0 + kv0 + kv) * 1024 + colBase + dg * 16;
      const u16x8 v0 = *(const u16x8*)(vrow);
      const u16x8 v1 = *(const u16x8*)(vrow + 8);
      char* vt = (char*)Vt;
#pragma unroll
      for (int j = 0; j < 8; j++) {
        *(unsigned short*)(vt + (dg * 16 + j) * 128 + ((kv * 2) ^ (j << 4))) = v0[j];
        *(unsigned short*)(vt + (dg * 16 + 8 + j) * 128 + ((kv * 2) ^ (j << 4))) = v1[j];
      }
    }
    __syncthreads();
    // QK^T : s[f] rows=q (hi*4+r), cols kv = f*16+lo
    f32x4 s[4];
    const char* ksb = (const char*)Ks;
#pragma unroll
    for (int f = 0; f < 4; f++) {
      s[f] = (f32x4){0.f, 0.f, 0.f, 0.f};
      const int kr = f * 16 + lo;
      const bf16x8 b0 = *(const bf16x8*)(ksb + kr * 128 + ((hi * 16) ^ ((kr & 7) << 4)));
      const bf16x8 b1 = *(const bf16x8*)(ksb + kr * 128 + ((64 + hi * 16) ^ ((kr & 7) << 4)));
      s[f] = __builtin_amdgcn_mfma_f32_16x16x32_bf16(qf0, b0, s[f], 0, 0, 0);
      s[f] = __builtin_amdgcn_mfma_f32_16x16x32_bf16(qf1, b1, s[f], 0, 0, 0);
    }
    // online softmax (scaled by 1/sqrt(64))
#pragma unroll
    for (int r = 0; r < 4; r++) {
      float mx = fmaxf(fmaxf(s[0][r], s[1][r]), fmaxf(s[2][r], s[3][r])) * 0.125f;
      mx = fmaxf(mx, __shfl_xor(mx, 1));
      mx = fmaxf(mx, __shfl_xor(mx, 2));
      mx = fmaxf(mx, __shfl_xor(mx, 4));
      mx = fmaxf(mx, __shfl_xor(mx, 8));
      const float mn = fmaxf(m_r[r], mx);
      const float al = __expf(m_r[r] - mn);
      float rsum = 0.f;
#pragma unroll
      for (int f = 0; f < 4; f++) {
        const float p = __expf(s[f][r] * 0.125f - mn);
        s[f][r] = p;
        rsum += p;
      }
      rsum += __shfl_xor(rsum, 1);
      rsum += __shfl_xor(rsum, 2);
      rsum += __shfl_xor(rsum, 4);
      rsum += __shfl_xor(rsum, 8);
      l_r[r] = l_r[r] * al + rsum;
      m_r[r] = mn;
#pragma unroll
      for (int d = 0; d < 4; d++) oacc[d][r] *= al;
    }
    // P -> LDS (bf16, swizzled), per-wave region
    char* psb = (char*)&Ps[w][0];
#pragma unroll
    for (int f = 0; f < 4; f++)
#pragma unroll
      for (int r = 0; r < 4; r++) {
        const int q = hi * 4 + r;
        const int kvb = (f * 16 + lo) * 2;
        *(unsigned short*)(psb + q * 128 + (kvb ^ ((q & 7) << 4))) = f2bf_bits(s[f][r]);
      }
    asm volatile("" ::: "memory");  // order LDS P writes before reads (same wave)
    // PV
#pragma unroll
    for (int ks = 0; ks < 2; ks++) {
      const int kbyte = ks * 64 + (hi << 4);
      const bf16x8 ap = *(const bf16x8*)(psb + lo * 128 + (kbyte ^ ((lo & 7) << 4)));
#pragma unroll
      for (int d = 0; d < 4; d++) {
        const int dr = d * 16 + lo;
        const bf16x8 bv = *(const bf16x8*)((const char*)Vt + dr * 128 + (kbyte ^ ((dr & 7) << 4)));
        oacc[d] = __builtin_amdgcn_mfma_f32_16x16x32_bf16(ap, bv, oacc[d], 0, 0, 0);
      }
    }
  }
  // epilogue
#pragma unroll
  for (int r = 0; r < 4; r++) {
    const float inv = 1.f / l_r[r];
    const size_t row = tRow0 + blockIdx.x * 64 + w * 16 + hi * 4 + r;
#pragma unroll
    for (int d = 0; d < 4; d++)
      O[row * 1024 + colBase + d * 16 + lo] = f2bf_bits(oacc[d][r] * inv);
  }
}

extern "C" void kernel_launch(void* const* d_in, const int* in_sizes, int n_in,
                              void* d_out, int out_size, void* d_ws, size_t ws_size,
                              hipStream_t stream) {
  (void)in_sizes; (void)n_in; (void)out_size; (void)ws_size;
  const float* x   = (const float*)d_in[0];
  const float* w_q = (const float*)d_in[2];
  const float* w_k = (const float*)d_in[3];
  const float* w_v = (const float*)d_in[4];
  const float* w_0 = (const float*)d_in[5];
  const float* b_0 = (const float*)d_in[6];
  const float* w_1 = (const float*)d_in[7];
  const float* b_1 = (const float*)d_in[8];
  const float* w_2 = (const float*)d_in[9];
  const float* b_2 = (const float*)d_in[10];
  const float* g_1 = (const float*)d_in[11];
  const float* be_1 = (const float*)d_in[12];
  const float* g_2 = (const float*)d_in[13];
  const float* be_2 = (const float*)d_in[14];

  char* ws = (char*)d_ws;
  size_t off = 0;
  auto alloc = [&](size_t bytes) {
    void* p = ws + off;
    off += (bytes + 255) & ~(size_t)255;
    return p;
  };
  const size_t MB = 1024 * 1024;
  unsigned short* wt_q = (unsigned short*)alloc(2 * MB);
  unsigned short* wt_k = (unsigned short*)alloc(2 * MB);
  unsigned short* wt_v = (unsigned short*)alloc(2 * MB);
  unsigned short* wt_0 = (unsigned short*)alloc(2 * MB);
  unsigned short* wt_1 = (unsigned short*)alloc(8 * MB);   // [4096][1024]
  unsigned short* wt_2 = (unsigned short*)alloc(8 * MB);   // [1024][4096]
  unsigned short* xn   = (unsigned short*)alloc(8 * MB);   // [4096][1024]
  unsigned short* Qb   = (unsigned short*)alloc(8 * MB);
  unsigned short* Kb   = (unsigned short*)alloc(8 * MB);
  unsigned short* Vb   = (unsigned short*)alloc(8 * MB);
  unsigned short* aO   = (unsigned short*)alloc(8 * MB);
  float*          x1f  = (float*)alloc(16 * MB);           // [4096][1024] f32
  unsigned short* ff1  = (unsigned short*)alloc(32 * MB);  // [4096][4096]

  // weights -> bf16 transposed
  wconv_t<<<dim3(32, 32), 256, 0, stream>>>(w_q, wt_q, 1024, 1024);
  wconv_t<<<dim3(32, 32), 256, 0, stream>>>(w_k, wt_k, 1024, 1024);
  wconv_t<<<dim3(32, 32), 256, 0, stream>>>(w_v, wt_v, 1024, 1024);
  wconv_t<<<dim3(32, 32), 256, 0, stream>>>(w_0, wt_0, 1024, 1024);
  wconv_t<<<dim3(128, 32), 256, 0, stream>>>(w_1, wt_1, 1024, 4096);
  wconv_t<<<dim3(32, 128), 256, 0, stream>>>(w_2, wt_2, 4096, 1024);

  // LN1
  ln_k<<<4096, 256, 0, stream>>>(x, g_1, be_1, xn);
  // QKV projections
  gemm_bt<0><<<dim3(8, 32), 256, 0, stream>>>(xn, wt_q, nullptr, nullptr, Qb, 4096, 1024, 1024);
  gemm_bt<0><<<dim3(8, 32), 256, 0, stream>>>(xn, wt_k, nullptr, nullptr, Kb, 4096, 1024, 1024);
  gemm_bt<0><<<dim3(8, 32), 256, 0, stream>>>(xn, wt_v, nullptr, nullptr, Vb, 4096, 1024, 1024);
  // attention
  attn_k<<<dim3(32, 16, 2), 256, 0, stream>>>(Qb, Kb, Vb, aO);
  // output proj + residual -> x1 (f32)
  gemm_bt<1><<<dim3(8, 32), 256, 0, stream>>>(aO, wt_0, b_0, x, x1f, 4096, 1024, 1024);
  // LN2
  ln_k<<<4096, 256, 0, stream>>>(x1f, g_2, be_2, xn);
  // FF1 + relu
  gemm_bt<2><<<dim3(32, 32), 256, 0, stream>>>(xn, wt_1, b_1, nullptr, ff1, 4096, 4096, 1024);
  // FF2 + bias + residual -> out (f32)
  gemm_bt<1><<<dim3(8, 32), 256, 0, stream>>>(ff1, wt_2, b_2, x1f, (float*)d_out, 4096, 1024, 4096);
}